// Round 1
// baseline (83.358 us; speedup 1.0000x reference)
//
#include <hip/hip_runtime.h>

// Problem constants (match reference setup_inputs)
#define BATCH   8
#define CIMG    3
#define HFULL   512
#define WFULL   512
#define HWFULL  (HFULL * WFULL)          // 262144
#define CFEAT   64
#define HE      128
#define WE      128
#define HWE     (HE * WE)                // 16384
#define NSEG    64
#define NBSEG   (BATCH * NSEG)           // 512
#define WALL_COT 0.5f
#define MIN_FRAC 0.01f

// ws float layout:
// [0]            recovery numerator  sum(mse * (mask>0))
// [1]            recovery denominator sum(mask>0)
// [2      .. 514)  per-(b,seg) counts
// [514    .. 1026) per-(b,seg) sum of reco_error
// [1026   .. 1538) per-(b,seg) pos pixel counts
#define WS_CNT  2
#define WS_SUM  (2 + NBSEG)
#define WS_POS  (2 + 2 * NBSEG)
#define WS_FLOATS (2 + 3 * NBSEG)

// Part B: 2,097,152 full-res pixels, 4 px/thread -> 524288 threads -> 2048 blocks
#define NBLK_B  2048
// Part A: 131,072 feature pixels, 4 px/thread -> 32768 threads -> 128 blocks
#define NBLK_A  128

__global__ __launch_bounds__(256) void confloss_main_kernel(
    const float* __restrict__ outputs, const float* __restrict__ inputs,
    const float* __restrict__ enc1,    const float* __restrict__ dec1,
    const float* __restrict__ masks,   const int* __restrict__ segs,
    float* __restrict__ ws)
{
    const int tid = threadIdx.x;

    if (blockIdx.x < NBLK_B) {
        // ---------------- Part B: recovery loss over full-res images ----------------
        const int g = blockIdx.x * 256 + tid;        // 4-pixel group index
        const int p = g * 4;                          // first pixel (flat over B*HW)
        const int b = p >> 18;                        // / 262144
        const int r = p & (HWFULL - 1);               // offset within plane

        const float4 m4 = *(const float4*)(masks + b * HWFULL + r);
        const float mv[4] = {m4.x, m4.y, m4.z, m4.w};

        float mse[4] = {0.f, 0.f, 0.f, 0.f};
        const float* ob = outputs + b * (CIMG * HWFULL) + r;
        const float* ib = inputs  + b * (CIMG * HWFULL) + r;
#pragma unroll
        for (int c = 0; c < CIMG; ++c) {
            const float4 o4 = *(const float4*)(ob + c * HWFULL);
            const float4 i4 = *(const float4*)(ib + c * HWFULL);
            const float ov[4] = {o4.x, o4.y, o4.z, o4.w};
            const float iv[4] = {i4.x, i4.y, i4.z, i4.w};
#pragma unroll
            for (int j = 0; j < 4; ++j) {
                const float tgt = (mv[j] >= WALL_COT) ? 0.0f : iv[j];
                const float d = ov[j] - tgt;
                mse[j] += d * d;
            }
        }
        float num = 0.f, den = 0.f;
#pragma unroll
        for (int j = 0; j < 4; ++j) {
            if (mv[j] > 0.0f) { num += mse[j]; den += 1.0f; }
        }

        // wave (64) reduce, then cross-wave via LDS
#pragma unroll
        for (int off = 32; off >= 1; off >>= 1) {
            num += __shfl_down(num, off);
            den += __shfl_down(den, off);
        }
        __shared__ float s_num[4], s_den[4];
        const int wid = tid >> 6;
        if ((tid & 63) == 0) { s_num[wid] = num; s_den[wid] = den; }
        __syncthreads();
        if (tid == 0) {
            float tn = s_num[0] + s_num[1] + s_num[2] + s_num[3];
            float td = s_den[0] + s_den[1] + s_den[2] + s_den[3];
            atomicAdd(&ws[0], tn);
            atomicAdd(&ws[1], td);
        }
    } else {
        // ---------------- Part A: segment stats at feature resolution ----------------
        const int a = blockIdx.x - NBLK_B;
        const int g = a * 256 + tid;                  // 4-pixel group
        const int p = g * 4;                          // flat over B*HE*WE
        const int b = p >> 14;                        // / 16384 (uniform per block)
        const int r = p & (HWE - 1);
        const int y = r >> 7;
        const int x = r & (WE - 1);

        const float* eb = enc1 + b * (CFEAT * HWE) + r;
        const float* db = dec1 + b * (CFEAT * HWE) + r;
        float acc[4] = {0.f, 0.f, 0.f, 0.f};
#pragma unroll 8
        for (int c = 0; c < CFEAT; ++c) {
            const float4 e4 = *(const float4*)(eb + c * HWE);
            const float4 d4 = *(const float4*)(db + c * HWE);
            float d0 = e4.x - d4.x; acc[0] += d0 * d0;
            float d1 = e4.y - d4.y; acc[1] += d1 * d1;
            float d2 = e4.z - d4.z; acc[2] += d2 * d2;
            float d3 = e4.w - d4.w; acc[3] += d3 * d3;
        }

        __shared__ float s_cnt[NSEG], s_sum[NSEG], s_pos[NSEG];
        if (tid < NSEG) { s_cnt[tid] = 0.f; s_sum[tid] = 0.f; s_pos[tid] = 0.f; }
        __syncthreads();

        // nearest-neighbor source index: (4y, 4(x+j)) in full res
        const int fullbase = b * HWFULL + (y * 4) * WFULL + x * 4;
#pragma unroll
        for (int j = 0; j < 4; ++j) {
            const int idx = fullbase + 4 * j;
            const int   seg = segs[idx];
            const float mk  = masks[idx];
            const float err = acc[j] * (1.0f / (float)CFEAT);
            atomicAdd(&s_cnt[seg], 1.0f);
            atomicAdd(&s_sum[seg], err);
            if (mk > 0.0f && mk < WALL_COT) atomicAdd(&s_pos[seg], 1.0f);
        }
        __syncthreads();

        if (tid < NSEG) {
            const int base = b * NSEG + tid;
            const float c = s_cnt[tid];
            if (c != 0.f) {
                atomicAdd(&ws[WS_CNT + base], c);
                atomicAdd(&ws[WS_SUM + base], s_sum[tid]);
                atomicAdd(&ws[WS_POS + base], s_pos[tid]);
            }
        }
    }
}

__global__ __launch_bounds__(512) void confloss_finalize_kernel(
    const float* __restrict__ ws, float* __restrict__ out)
{
    const int t = threadIdx.x;   // 512 threads, one per (b,seg)
    const float cnt = ws[WS_CNT + t];
    const float sum = ws[WS_SUM + t];
    const float pos = ws[WS_POS + t];
    const float safe = fmaxf(cnt, 1.0f);
    const float mean = sum / safe;
    const bool valid = (cnt / (float)HWE) >= MIN_FRAC;
    const bool posf  = (pos / safe) > MIN_FRAC;
    float sel = (valid && posf) ? 1.0f : 0.0f;
    float val = mean * sel;

#pragma unroll
    for (int off = 32; off >= 1; off >>= 1) {
        val += __shfl_down(val, off);
        sel += __shfl_down(sel, off);
    }
    __shared__ float sv[8], ss[8];
    const int wid = t >> 6;
    if ((t & 63) == 0) { sv[wid] = val; ss[wid] = sel; }
    __syncthreads();
    if (t == 0) {
        float tv = 0.f, ts = 0.f;
#pragma unroll
        for (int w = 0; w < 8; ++w) { tv += sv[w]; ts += ss[w]; }
        const float flat_pos_mean = tv / fmaxf(ts, 1.0f);
        const float loss_recov = ws[0] / fmaxf(ws[1], 1.0f);
        out[0] = loss_recov + flat_pos_mean;
    }
}

extern "C" void kernel_launch(void* const* d_in, const int* in_sizes, int n_in,
                              void* d_out, int out_size, void* d_ws, size_t ws_size,
                              hipStream_t stream) {
    const float* outputs = (const float*)d_in[0];
    const float* inputs  = (const float*)d_in[1];
    const float* enc1    = (const float*)d_in[2];
    const float* dec1    = (const float*)d_in[3];
    const float* masks   = (const float*)d_in[4];
    const int*   segs    = (const int*)d_in[5];
    float* ws  = (float*)d_ws;
    float* out = (float*)d_out;

    // accumulators must be zeroed every call (harness poisons ws once, never re-zeros)
    hipMemsetAsync(ws, 0, WS_FLOATS * sizeof(float), stream);

    confloss_main_kernel<<<NBLK_B + NBLK_A, 256, 0, stream>>>(
        outputs, inputs, enc1, dec1, masks, segs, ws);
    confloss_finalize_kernel<<<1, 512, 0, stream>>>(ws, out);
}

// Round 2
// 76.655 us; speedup vs baseline: 1.0874x; 1.0874x over previous
//
#include <hip/hip_runtime.h>

// Problem constants (match reference setup_inputs)
#define BATCH   8
#define CIMG    3
#define HFULL   512
#define WFULL   512
#define HWFULL  (HFULL * WFULL)          // 262144
#define CFEAT   64
#define HE      128
#define WE      128
#define HWE     (HE * WE)                // 16384
#define NSEG    64
#define NBSEG   (BATCH * NSEG)           // 512
#define WALL_COT 0.5f
#define MIN_FRAC 0.01f

// ws float layout:
// [0]            recovery numerator  sum(mse * (mask>0))
// [1]            recovery denominator sum(mask>0)
// [2      .. 514)  per-(b,seg) counts
// [514    .. 1026) per-(b,seg) sum of reco_error
// [1026   .. 1538) per-(b,seg) pos pixel counts
#define WS_CNT  2
#define WS_SUM  (2 + NBSEG)
#define WS_POS  (2 + 2 * NBSEG)
#define WS_FLOATS (2 + 3 * NBSEG)

// Part A: 131,072 feature pixels. Block = 256 pixels, channels split across
// the 4 waves (wave w -> channels [16w,16w+16)). 512 blocks, dispatched FIRST
// (longest waves start early instead of running as a tail).
#define NBLK_A  512
// Part B: 2,097,152 full-res pixels, 4 px/thread -> 2048 blocks
#define NBLK_B  2048

__global__ __launch_bounds__(256) void confloss_main_kernel(
    const float* __restrict__ outputs, const float* __restrict__ inputs,
    const float* __restrict__ enc1,    const float* __restrict__ dec1,
    const float* __restrict__ masks,   const int* __restrict__ segs,
    float* __restrict__ ws)
{
    const int tid = threadIdx.x;

    if (blockIdx.x < NBLK_A) {
        // ---------------- Part A: segment stats at feature resolution ----------------
        // Block covers 256 consecutive feature pixels (64 groups of 4).
        // thread t: pixel-group (t&63), wave (t>>6) owns a 16-channel slice.
        const int a    = blockIdx.x;
        const int grp  = tid & 63;
        const int w    = tid >> 6;
        const int pbase = a * 256;                 // first pixel (flat over B*HWE)
        const int b    = pbase >> 14;              // uniform per block (256 | 16384)
        const int rblk = pbase & (HWE - 1);
        const int r    = rblk + grp * 4;           // this group's first pixel in plane

        __shared__ float  s_cnt[NSEG], s_sum[NSEG], s_pos[NSEG];
        __shared__ float4 s_part[4][64];
        if (tid < NSEG) { s_cnt[tid] = 0.f; s_sum[tid] = 0.f; s_pos[tid] = 0.f; }

        const size_t planes = (size_t)b * (CFEAT * HWE) + (size_t)(w * 16) * HWE + r;
        const float* eb = enc1 + planes;
        const float* db = dec1 + planes;
        float4 acc = make_float4(0.f, 0.f, 0.f, 0.f);
#pragma unroll
        for (int c = 0; c < 16; ++c) {
            const float4 e4 = *(const float4*)(eb + c * HWE);
            const float4 d4 = *(const float4*)(db + c * HWE);
            float d0 = e4.x - d4.x; acc.x += d0 * d0;
            float d1 = e4.y - d4.y; acc.y += d1 * d1;
            float d2 = e4.z - d4.z; acc.z += d2 * d2;
            float d3 = e4.w - d4.w; acc.w += d3 * d3;
        }
        s_part[w][grp] = acc;
        __syncthreads();

        if (w == 0) {
            const float4 p0 = s_part[0][grp];
            const float4 p1 = s_part[1][grp];
            const float4 p2 = s_part[2][grp];
            const float4 p3 = s_part[3][grp];
            const float err[4] = {
                (p0.x + p1.x + p2.x + p3.x) * (1.0f / (float)CFEAT),
                (p0.y + p1.y + p2.y + p3.y) * (1.0f / (float)CFEAT),
                (p0.z + p1.z + p2.z + p3.z) * (1.0f / (float)CFEAT),
                (p0.w + p1.w + p2.w + p3.w) * (1.0f / (float)CFEAT)};
            // nearest-neighbor source at full res: (4y, 4(x+j))
            const int y = r >> 7;
            const int x = r & (WE - 1);
            const int fullbase = b * HWFULL + (y * 4) * WFULL + x * 4;
#pragma unroll
            for (int j = 0; j < 4; ++j) {
                const int   idx = fullbase + 4 * j;
                const int   seg = segs[idx];
                const float mk  = masks[idx];
                atomicAdd(&s_cnt[seg], 1.0f);
                atomicAdd(&s_sum[seg], err[j]);
                if (mk > 0.0f && mk < WALL_COT) atomicAdd(&s_pos[seg], 1.0f);
            }
        }
        __syncthreads();

        if (tid < NSEG) {
            const int base = b * NSEG + tid;
            atomicAdd(&ws[WS_CNT + base], s_cnt[tid]);
            atomicAdd(&ws[WS_SUM + base], s_sum[tid]);
            atomicAdd(&ws[WS_POS + base], s_pos[tid]);
        }
    } else {
        // ---------------- Part B: recovery loss over full-res images ----------------
        const int g = (blockIdx.x - NBLK_A) * 256 + tid;  // 4-pixel group index
        const int p = g * 4;                              // flat over B*HW
        const int b = p >> 18;                            // / 262144
        const int r = p & (HWFULL - 1);

        const float4 m4 = *(const float4*)(masks + b * HWFULL + r);
        const float mv[4] = {m4.x, m4.y, m4.z, m4.w};

        float mse[4] = {0.f, 0.f, 0.f, 0.f};
        const float* ob = outputs + b * (CIMG * HWFULL) + r;
        const float* ib = inputs  + b * (CIMG * HWFULL) + r;
#pragma unroll
        for (int c = 0; c < CIMG; ++c) {
            const float4 o4 = *(const float4*)(ob + c * HWFULL);
            const float4 i4 = *(const float4*)(ib + c * HWFULL);
            const float ov[4] = {o4.x, o4.y, o4.z, o4.w};
            const float iv[4] = {i4.x, i4.y, i4.z, i4.w};
#pragma unroll
            for (int j = 0; j < 4; ++j) {
                const float tgt = (mv[j] >= WALL_COT) ? 0.0f : iv[j];
                const float d = ov[j] - tgt;
                mse[j] += d * d;
            }
        }
        float num = 0.f, den = 0.f;
#pragma unroll
        for (int j = 0; j < 4; ++j) {
            if (mv[j] > 0.0f) { num += mse[j]; den += 1.0f; }
        }

        // wave (64) reduce, then cross-wave via LDS
#pragma unroll
        for (int off = 32; off >= 1; off >>= 1) {
            num += __shfl_down(num, off);
            den += __shfl_down(den, off);
        }
        __shared__ float s_num[4], s_den[4];
        const int wid = tid >> 6;
        if ((tid & 63) == 0) { s_num[wid] = num; s_den[wid] = den; }
        __syncthreads();
        if (tid == 0) {
            float tn = s_num[0] + s_num[1] + s_num[2] + s_num[3];
            float td = s_den[0] + s_den[1] + s_den[2] + s_den[3];
            atomicAdd(&ws[0], tn);
            atomicAdd(&ws[1], td);
        }
    }
}

__global__ __launch_bounds__(512) void confloss_finalize_kernel(
    const float* __restrict__ ws, float* __restrict__ out)
{
    const int t = threadIdx.x;   // 512 threads, one per (b,seg)
    const float cnt = ws[WS_CNT + t];
    const float sum = ws[WS_SUM + t];
    const float pos = ws[WS_POS + t];
    const float safe = fmaxf(cnt, 1.0f);
    const float mean = sum / safe;
    const bool valid = (cnt / (float)HWE) >= MIN_FRAC;
    const bool posf  = (pos / safe) > MIN_FRAC;
    float sel = (valid && posf) ? 1.0f : 0.0f;
    float val = mean * sel;

#pragma unroll
    for (int off = 32; off >= 1; off >>= 1) {
        val += __shfl_down(val, off);
        sel += __shfl_down(sel, off);
    }
    __shared__ float sv[8], ss[8];
    const int wid = t >> 6;
    if ((t & 63) == 0) { sv[wid] = val; ss[wid] = sel; }
    __syncthreads();
    if (t == 0) {
        float tv = 0.f, ts = 0.f;
#pragma unroll
        for (int w = 0; w < 8; ++w) { tv += sv[w]; ts += ss[w]; }
        const float flat_pos_mean = tv / fmaxf(ts, 1.0f);
        const float loss_recov = ws[0] / fmaxf(ws[1], 1.0f);
        out[0] = loss_recov + flat_pos_mean;
    }
}

extern "C" void kernel_launch(void* const* d_in, const int* in_sizes, int n_in,
                              void* d_out, int out_size, void* d_ws, size_t ws_size,
                              hipStream_t stream) {
    const float* outputs = (const float*)d_in[0];
    const float* inputs  = (const float*)d_in[1];
    const float* enc1    = (const float*)d_in[2];
    const float* dec1    = (const float*)d_in[3];
    const float* masks   = (const float*)d_in[4];
    const int*   segs    = (const int*)d_in[5];
    float* ws  = (float*)d_ws;
    float* out = (float*)d_out;

    // accumulators must be zeroed every call (harness poisons ws once, never re-zeros)
    hipMemsetAsync(ws, 0, WS_FLOATS * sizeof(float), stream);

    confloss_main_kernel<<<NBLK_A + NBLK_B, 256, 0, stream>>>(
        outputs, inputs, enc1, dec1, masks, segs, ws);
    confloss_finalize_kernel<<<1, 512, 0, stream>>>(ws, out);
}

// Round 3
// 71.855 us; speedup vs baseline: 1.1601x; 1.0668x over previous
//
#include <hip/hip_runtime.h>

// Problem constants (match reference setup_inputs)
#define BATCH   8
#define CIMG    3
#define HFULL   512
#define WFULL   512
#define HWFULL  (HFULL * WFULL)          // 262144
#define CFEAT   64
#define HE      128
#define WE      128
#define HWE     (HE * WE)                // 16384
#define NSEG    64
#define NBSEG   (BATCH * NSEG)           // 512
#define WALL_COT 0.5f
#define MIN_FRAC 0.01f

// ws float layout:
// [0]            recovery numerator  sum(mse * (mask>0))
// [1]            recovery denominator sum(mask>0)
// [2      .. 514)  per-(b,seg) counts
// [514    .. 1026) per-(b,seg) sum of reco_error (accumulated in channel partials)
// [1026   .. 1538) per-(b,seg) pos pixel counts
#define WS_CNT  2
#define WS_SUM  (2 + NBSEG)
#define WS_POS  (2 + 2 * NBSEG)
#define WS_FLOATS (2 + 3 * NBSEG)

// Part A: 131,072 feature pixels x 64 channels, split as
//   (pixel-tile pt in [0,512)) x (channel-slice cs in [0,4), 16 ch each).
//   Block = 256 pixels x 16 channels = 32 KB enc + 32 KB dec... per-thread:
//   thread t: pixel-group (t&63) [4 px], channel-sub (t>>6) [4 ch] -> 8 float4 loads.
// Part B: 2,097,152 full-res pixels, 4 px/thread -> 2048 blocks, 7 float4 loads/thread.
// Blocks interleaved even/odd so every CU gets a uniform mix; all blocks ~30 KB.
#define NBLK_A  2048
#define NBLK_B  2048

__global__ __launch_bounds__(256) void confloss_main_kernel(
    const float* __restrict__ outputs, const float* __restrict__ inputs,
    const float* __restrict__ enc1,    const float* __restrict__ dec1,
    const float* __restrict__ masks,   const int* __restrict__ segs,
    float* __restrict__ ws)
{
    const int tid = threadIdx.x;
    const int idx = blockIdx.x >> 1;

    if ((blockIdx.x & 1) == 0) {
        // ---------------- Part A: segment stats at feature resolution ----------------
        const int pt  = idx >> 2;          // pixel tile [0,512)
        const int cs  = idx & 3;           // channel slice [0,4)
        const int grp = tid & 63;          // float4 pixel group within tile
        const int sub = tid >> 6;          // 4-channel sub-slice within the 16
        const int pbase = pt * 256;        // first pixel (flat over B*HWE)
        const int b  = pbase >> 14;        // uniform per block (256 | 16384)
        const int r  = (pbase & (HWE - 1)) + grp * 4;
        const int c0 = cs * 16 + sub * 4;

        __shared__ float  s_cnt[NSEG], s_sum[NSEG], s_pos[NSEG];
        __shared__ float4 s_part[4][64];
        if (tid < NSEG) { s_sum[tid] = 0.f; s_cnt[tid] = 0.f; s_pos[tid] = 0.f; }

        const size_t base = ((size_t)b * CFEAT + c0) * HWE + r;
        const float* eb = enc1 + base;
        const float* db = dec1 + base;
        // 8 independent loads upfront -> max memory-level parallelism
        const float4 e0 = *(const float4*)(eb + 0 * HWE);
        const float4 e1 = *(const float4*)(eb + 1 * HWE);
        const float4 e2 = *(const float4*)(eb + 2 * HWE);
        const float4 e3 = *(const float4*)(eb + 3 * HWE);
        const float4 d0 = *(const float4*)(db + 0 * HWE);
        const float4 d1 = *(const float4*)(db + 1 * HWE);
        const float4 d2 = *(const float4*)(db + 2 * HWE);
        const float4 d3 = *(const float4*)(db + 3 * HWE);

        float4 acc;
        float t0, t1, t2, t3;
        t0 = e0.x - d0.x; t1 = e1.x - d1.x; t2 = e2.x - d2.x; t3 = e3.x - d3.x;
        acc.x = t0 * t0 + t1 * t1 + t2 * t2 + t3 * t3;
        t0 = e0.y - d0.y; t1 = e1.y - d1.y; t2 = e2.y - d2.y; t3 = e3.y - d3.y;
        acc.y = t0 * t0 + t1 * t1 + t2 * t2 + t3 * t3;
        t0 = e0.z - d0.z; t1 = e1.z - d1.z; t2 = e2.z - d2.z; t3 = e3.z - d3.z;
        acc.z = t0 * t0 + t1 * t1 + t2 * t2 + t3 * t3;
        t0 = e0.w - d0.w; t1 = e1.w - d1.w; t2 = e2.w - d2.w; t3 = e3.w - d3.w;
        acc.w = t0 * t0 + t1 * t1 + t2 * t2 + t3 * t3;

        s_part[sub][grp] = acc;
        __syncthreads();

        if (sub == 0) {   // wave 0: per-pixel partial err over this block's 16 channels
            const float4 p0 = s_part[0][grp];
            const float4 p1 = s_part[1][grp];
            const float4 p2 = s_part[2][grp];
            const float4 p3 = s_part[3][grp];
            const float err[4] = {
                (p0.x + p1.x + p2.x + p3.x) * (1.0f / (float)CFEAT),
                (p0.y + p1.y + p2.y + p3.y) * (1.0f / (float)CFEAT),
                (p0.z + p1.z + p2.z + p3.z) * (1.0f / (float)CFEAT),
                (p0.w + p1.w + p2.w + p3.w) * (1.0f / (float)CFEAT)};
            // nearest-neighbor source at full res: (4y, 4(x+j))
            const int y = r >> 7;
            const int x = r & (WE - 1);
            const int fullbase = b * HWFULL + (y * 4) * WFULL + x * 4;
#pragma unroll
            for (int j = 0; j < 4; ++j) {
                const int ii  = fullbase + 4 * j;
                const int seg = segs[ii];
                atomicAdd(&s_sum[seg], err[j]);
                if (cs == 0) {
                    const float mk = masks[ii];
                    atomicAdd(&s_cnt[seg], 1.0f);
                    if (mk > 0.0f && mk < WALL_COT) atomicAdd(&s_pos[seg], 1.0f);
                }
            }
        }
        __syncthreads();

        if (tid < NSEG) {
            const int gbase = b * NSEG + tid;
            atomicAdd(&ws[WS_SUM + gbase], s_sum[tid]);
            if (cs == 0) {
                atomicAdd(&ws[WS_CNT + gbase], s_cnt[tid]);
                atomicAdd(&ws[WS_POS + gbase], s_pos[tid]);
            }
        }
    } else {
        // ---------------- Part B: recovery loss over full-res images ----------------
        const int g = idx * 256 + tid;     // 4-pixel group index
        const int p = g * 4;               // flat over B*HW
        const int b = p >> 18;             // / 262144
        const int r = p & (HWFULL - 1);

        const float* ob = outputs + b * (CIMG * HWFULL) + r;
        const float* ib = inputs  + b * (CIMG * HWFULL) + r;
        // 7 independent loads upfront
        const float4 m4 = *(const float4*)(masks + b * HWFULL + r);
        const float4 o0 = *(const float4*)(ob + 0 * HWFULL);
        const float4 o1 = *(const float4*)(ob + 1 * HWFULL);
        const float4 o2 = *(const float4*)(ob + 2 * HWFULL);
        const float4 i0 = *(const float4*)(ib + 0 * HWFULL);
        const float4 i1 = *(const float4*)(ib + 1 * HWFULL);
        const float4 i2 = *(const float4*)(ib + 2 * HWFULL);

        const float mv[4] = {m4.x, m4.y, m4.z, m4.w};
        const float ov[3][4] = {{o0.x,o0.y,o0.z,o0.w},{o1.x,o1.y,o1.z,o1.w},{o2.x,o2.y,o2.z,o2.w}};
        const float iv[3][4] = {{i0.x,i0.y,i0.z,i0.w},{i1.x,i1.y,i1.z,i1.w},{i2.x,i2.y,i2.z,i2.w}};

        float num = 0.f, den = 0.f;
#pragma unroll
        for (int j = 0; j < 4; ++j) {
            float mse = 0.f;
#pragma unroll
            for (int c = 0; c < CIMG; ++c) {
                const float tgt = (mv[j] >= WALL_COT) ? 0.0f : iv[c][j];
                const float d = ov[c][j] - tgt;
                mse += d * d;
            }
            if (mv[j] > 0.0f) { num += mse; den += 1.0f; }
        }

        // wave (64) reduce, then cross-wave via LDS
#pragma unroll
        for (int off = 32; off >= 1; off >>= 1) {
            num += __shfl_down(num, off);
            den += __shfl_down(den, off);
        }
        __shared__ float s_num[4], s_den[4];
        const int wid = tid >> 6;
        if ((tid & 63) == 0) { s_num[wid] = num; s_den[wid] = den; }
        __syncthreads();
        if (tid == 0) {
            float tn = s_num[0] + s_num[1] + s_num[2] + s_num[3];
            float td = s_den[0] + s_den[1] + s_den[2] + s_den[3];
            atomicAdd(&ws[0], tn);
            atomicAdd(&ws[1], td);
        }
    }
}

__global__ __launch_bounds__(512) void confloss_finalize_kernel(
    const float* __restrict__ ws, float* __restrict__ out)
{
    const int t = threadIdx.x;   // 512 threads, one per (b,seg)
    const float cnt = ws[WS_CNT + t];
    const float sum = ws[WS_SUM + t];
    const float pos = ws[WS_POS + t];
    const float safe = fmaxf(cnt, 1.0f);
    const float mean = sum / safe;
    const bool valid = (cnt / (float)HWE) >= MIN_FRAC;
    const bool posf  = (pos / safe) > MIN_FRAC;
    float sel = (valid && posf) ? 1.0f : 0.0f;
    float val = mean * sel;

#pragma unroll
    for (int off = 32; off >= 1; off >>= 1) {
        val += __shfl_down(val, off);
        sel += __shfl_down(sel, off);
    }
    __shared__ float sv[8], ss[8];
    const int wid = t >> 6;
    if ((t & 63) == 0) { sv[wid] = val; ss[wid] = sel; }
    __syncthreads();
    if (t == 0) {
        float tv = 0.f, ts = 0.f;
#pragma unroll
        for (int w = 0; w < 8; ++w) { tv += sv[w]; ts += ss[w]; }
        const float flat_pos_mean = tv / fmaxf(ts, 1.0f);
        const float loss_recov = ws[0] / fmaxf(ws[1], 1.0f);
        out[0] = loss_recov + flat_pos_mean;
    }
}

extern "C" void kernel_launch(void* const* d_in, const int* in_sizes, int n_in,
                              void* d_out, int out_size, void* d_ws, size_t ws_size,
                              hipStream_t stream) {
    const float* outputs = (const float*)d_in[0];
    const float* inputs  = (const float*)d_in[1];
    const float* enc1    = (const float*)d_in[2];
    const float* dec1    = (const float*)d_in[3];
    const float* masks   = (const float*)d_in[4];
    const int*   segs    = (const int*)d_in[5];
    float* ws  = (float*)d_ws;
    float* out = (float*)d_out;

    // accumulators must be zeroed every call (harness poisons ws once, never re-zeros)
    hipMemsetAsync(ws, 0, WS_FLOATS * sizeof(float), stream);

    confloss_main_kernel<<<NBLK_A + NBLK_B, 256, 0, stream>>>(
        outputs, inputs, enc1, dec1, masks, segs, ws);
    confloss_finalize_kernel<<<1, 512, 0, stream>>>(ws, out);
}

// Round 4
// 36.684 us; speedup vs baseline: 2.2723x; 1.9587x over previous
//
#include <hip/hip_runtime.h>

// Problem constants (match reference setup_inputs)
#define BATCH   8
#define CIMG    3
#define HFULL   512
#define WFULL   512
#define HWFULL  (HFULL * WFULL)          // 262144
#define CFEAT   64
#define HE      128
#define WE      128
#define HWE     (HE * WE)                // 16384
#define NSEG    64
#define NBSEG   (BATCH * NSEG)           // 512
#define WALL_COT 0.5f
#define MIN_FRAC 0.01f

#define NBLK    2048                     // 2048 blocks x 256 threads = 524288 threads

// ws float layout:
// [0    .. 512)   per-(b,seg) counts          (atomic)
// [512  .. 1024)  per-(b,seg) sum reco_error  (atomic, channel partials)
// [1024 .. 1536)  per-(b,seg) pos counts      (atomic)
// [1536 .. 3584)  per-block recovery numerator   (plain store)
// [3584 .. 5632)  per-block recovery denominator (plain store)
#define WS_CNT   0
#define WS_SUM   NBSEG
#define WS_POS   (2 * NBSEG)
#define WS_BNUM  (3 * NBSEG)
#define WS_BDEN  (3 * NBSEG + NBLK)
#define WS_ZERO_FLOATS (3 * NBSEG)       // only the atomic bins need zeroing

// Every thread does ONE A-task (4 px x 4 ch of enc/dec) and ONE B-task (4 px
// full-res recovery): ~19 independent float4/dword loads issued upfront.
// __launch_bounds__(256,2): min 2 waves/EU -> compiler may use ~256 VGPRs ->
// scheduler keeps the loads in flight instead of register-minimizing.
__global__ __launch_bounds__(256, 2) void confloss_main_kernel(
    const float* __restrict__ outputs, const float* __restrict__ inputs,
    const float* __restrict__ enc1,    const float* __restrict__ dec1,
    const float* __restrict__ masks,   const int* __restrict__ segs,
    float* __restrict__ ws)
{
    const int tid = threadIdx.x;
    const int i   = blockIdx.x * 256 + tid;

    __shared__ float s_cnt[NSEG], s_sum[NSEG], s_pos[NSEG];
    __shared__ float s_rn[4], s_rd[4];
    if (tid < NSEG) { s_cnt[tid] = 0.f; s_sum[tid] = 0.f; s_pos[tid] = 0.f; }
    __syncthreads();

    // ---- A-task decode: px-group g (4 px), channel-sub c (4 ch) ----
    const int g  = i & 32767;            // [0, 32768) : 8 batches x 4096 groups
    const int c  = i >> 15;              // [0, 16)    : 4-channel slice
    const int ba = g >> 12;              // batch (uniform per block)
    const int ra = (g & 4095) * 4;       // px offset in 128x128 plane
    const size_t abase = ((size_t)ba * CFEAT + (size_t)c * 4) * HWE + ra;
    const float* ep = enc1 + abase;
    const float* dp = dec1 + abase;
    // nearest-neighbor full-res source: rows 4y, cols 4x+{0,4,8,12} -> one 64B line
    const int ya = ra >> 7, xa = ra & (WE - 1);
    const int fb = ba * HWFULL + (ya * 4) * WFULL + xa * 4;
    const bool duty = (c == (g & 15));   // exactly one c-slice counts each px-group

    // ---- B-task decode: 4 full-res px ----
    const int bb = i >> 16;              // batch
    const int rb = (i & 65535) * 4;      // px offset in 512x512 plane
    const float* ob = outputs + (size_t)bb * (CIMG * HWFULL) + rb;
    const float* ib = inputs  + (size_t)bb * (CIMG * HWFULL) + rb;

    // ---- issue ALL independent loads upfront ----
    const float4 e0 = *(const float4*)(ep);
    const float4 e1 = *(const float4*)(ep + HWE);
    const float4 e2 = *(const float4*)(ep + 2 * HWE);
    const float4 e3 = *(const float4*)(ep + 3 * HWE);
    const float4 d0 = *(const float4*)(dp);
    const float4 d1 = *(const float4*)(dp + HWE);
    const float4 d2 = *(const float4*)(dp + 2 * HWE);
    const float4 d3 = *(const float4*)(dp + 3 * HWE);
    const float4 mB = *(const float4*)(masks + (size_t)bb * HWFULL + rb);
    const float4 o0 = *(const float4*)(ob);
    const float4 o1 = *(const float4*)(ob + HWFULL);
    const float4 o2 = *(const float4*)(ob + 2 * HWFULL);
    const float4 i0 = *(const float4*)(ib);
    const float4 i1 = *(const float4*)(ib + HWFULL);
    const float4 i2 = *(const float4*)(ib + 2 * HWFULL);
    const int s0 = segs[fb], s1 = segs[fb + 4], s2 = segs[fb + 8], s3 = segs[fb + 12];
    float mk0 = 1.f, mk1 = 1.f, mk2 = 1.f, mk3 = 1.f;
    if (duty) {
        mk0 = masks[fb];     mk1 = masks[fb + 4];
        mk2 = masks[fb + 8]; mk3 = masks[fb + 12];
    }

    // ---- B consume: recovery loss partials (registers only) ----
    float num = 0.f, den = 0.f;
    {
        float tgt, dd, mse;
        mse = 0.f;
        tgt = (mB.x >= WALL_COT) ? 0.f : i0.x; dd = o0.x - tgt; mse += dd * dd;
        tgt = (mB.x >= WALL_COT) ? 0.f : i1.x; dd = o1.x - tgt; mse += dd * dd;
        tgt = (mB.x >= WALL_COT) ? 0.f : i2.x; dd = o2.x - tgt; mse += dd * dd;
        if (mB.x > 0.f) { num += mse; den += 1.f; }
        mse = 0.f;
        tgt = (mB.y >= WALL_COT) ? 0.f : i0.y; dd = o0.y - tgt; mse += dd * dd;
        tgt = (mB.y >= WALL_COT) ? 0.f : i1.y; dd = o1.y - tgt; mse += dd * dd;
        tgt = (mB.y >= WALL_COT) ? 0.f : i2.y; dd = o2.y - tgt; mse += dd * dd;
        if (mB.y > 0.f) { num += mse; den += 1.f; }
        mse = 0.f;
        tgt = (mB.z >= WALL_COT) ? 0.f : i0.z; dd = o0.z - tgt; mse += dd * dd;
        tgt = (mB.z >= WALL_COT) ? 0.f : i1.z; dd = o1.z - tgt; mse += dd * dd;
        tgt = (mB.z >= WALL_COT) ? 0.f : i2.z; dd = o2.z - tgt; mse += dd * dd;
        if (mB.z > 0.f) { num += mse; den += 1.f; }
        mse = 0.f;
        tgt = (mB.w >= WALL_COT) ? 0.f : i0.w; dd = o0.w - tgt; mse += dd * dd;
        tgt = (mB.w >= WALL_COT) ? 0.f : i1.w; dd = o1.w - tgt; mse += dd * dd;
        tgt = (mB.w >= WALL_COT) ? 0.f : i2.w; dd = o2.w - tgt; mse += dd * dd;
        if (mB.w > 0.f) { num += mse; den += 1.f; }
    }

    // ---- A consume: per-px 4-channel error partials, binned directly ----
    {
        float t0, t1, t2, t3;
        t0 = e0.x - d0.x; t1 = e1.x - d1.x; t2 = e2.x - d2.x; t3 = e3.x - d3.x;
        const float p0 = (t0*t0 + t1*t1 + t2*t2 + t3*t3) * (1.0f / (float)CFEAT);
        t0 = e0.y - d0.y; t1 = e1.y - d1.y; t2 = e2.y - d2.y; t3 = e3.y - d3.y;
        const float p1 = (t0*t0 + t1*t1 + t2*t2 + t3*t3) * (1.0f / (float)CFEAT);
        t0 = e0.z - d0.z; t1 = e1.z - d1.z; t2 = e2.z - d2.z; t3 = e3.z - d3.z;
        const float p2 = (t0*t0 + t1*t1 + t2*t2 + t3*t3) * (1.0f / (float)CFEAT);
        t0 = e0.w - d0.w; t1 = e1.w - d1.w; t2 = e2.w - d2.w; t3 = e3.w - d3.w;
        const float p3 = (t0*t0 + t1*t1 + t2*t2 + t3*t3) * (1.0f / (float)CFEAT);
        atomicAdd(&s_sum[s0], p0);
        atomicAdd(&s_sum[s1], p1);
        atomicAdd(&s_sum[s2], p2);
        atomicAdd(&s_sum[s3], p3);
        if (duty) {
            atomicAdd(&s_cnt[s0], 1.f); if (mk0 > 0.f && mk0 < WALL_COT) atomicAdd(&s_pos[s0], 1.f);
            atomicAdd(&s_cnt[s1], 1.f); if (mk1 > 0.f && mk1 < WALL_COT) atomicAdd(&s_pos[s1], 1.f);
            atomicAdd(&s_cnt[s2], 1.f); if (mk2 > 0.f && mk2 < WALL_COT) atomicAdd(&s_pos[s2], 1.f);
            atomicAdd(&s_cnt[s3], 1.f); if (mk3 > 0.f && mk3 < WALL_COT) atomicAdd(&s_pos[s3], 1.f);
        }
    }

    // ---- B wave reduce -> per-block partial (plain store, no contention) ----
#pragma unroll
    for (int off = 32; off >= 1; off >>= 1) {
        num += __shfl_down(num, off);
        den += __shfl_down(den, off);
    }
    if ((tid & 63) == 0) { s_rn[tid >> 6] = num; s_rd[tid >> 6] = den; }
    __syncthreads();

    if (tid == 0) {
        ws[WS_BNUM + blockIdx.x] = s_rn[0] + s_rn[1] + s_rn[2] + s_rn[3];
        ws[WS_BDEN + blockIdx.x] = s_rd[0] + s_rd[1] + s_rd[2] + s_rd[3];
    }
    if (tid < NSEG) {
        const int gb = ba * NSEG + tid;
        atomicAdd(&ws[WS_SUM + gb], s_sum[tid]);
        const float cv = s_cnt[tid];
        if (cv != 0.f) atomicAdd(&ws[WS_CNT + gb], cv);
        const float pv = s_pos[tid];
        if (pv != 0.f) atomicAdd(&ws[WS_POS + gb], pv);
    }
}

__global__ __launch_bounds__(512) void confloss_finalize_kernel(
    const float* __restrict__ ws, float* __restrict__ out)
{
    const int t = threadIdx.x;   // 512 threads: one per (b,seg), 4 blocks' B-partials each
    float rn = 0.f, rd = 0.f;
#pragma unroll
    for (int k = 0; k < NBLK / 512; ++k) {
        rn += ws[WS_BNUM + t + k * 512];
        rd += ws[WS_BDEN + t + k * 512];
    }
    const float cnt = ws[WS_CNT + t];
    const float sum = ws[WS_SUM + t];
    const float pos = ws[WS_POS + t];
    const float safe = fmaxf(cnt, 1.0f);
    const float mean = sum / safe;
    const bool valid = (cnt / (float)HWE) >= MIN_FRAC;
    const bool posf  = (pos / safe) > MIN_FRAC;
    float sel = (valid && posf) ? 1.0f : 0.0f;
    float val = mean * sel;

#pragma unroll
    for (int off = 32; off >= 1; off >>= 1) {
        val += __shfl_down(val, off);
        sel += __shfl_down(sel, off);
        rn  += __shfl_down(rn,  off);
        rd  += __shfl_down(rd,  off);
    }
    __shared__ float sv[8], ss[8], sn[8], sd[8];
    const int wid = t >> 6;
    if ((t & 63) == 0) { sv[wid] = val; ss[wid] = sel; sn[wid] = rn; sd[wid] = rd; }
    __syncthreads();
    if (t == 0) {
        float tv = 0.f, ts = 0.f, tn = 0.f, td = 0.f;
#pragma unroll
        for (int w = 0; w < 8; ++w) { tv += sv[w]; ts += ss[w]; tn += sn[w]; td += sd[w]; }
        const float flat_pos_mean = tv / fmaxf(ts, 1.0f);
        const float loss_recov = tn / fmaxf(td, 1.0f);
        out[0] = loss_recov + flat_pos_mean;
    }
}

extern "C" void kernel_launch(void* const* d_in, const int* in_sizes, int n_in,
                              void* d_out, int out_size, void* d_ws, size_t ws_size,
                              hipStream_t stream) {
    const float* outputs = (const float*)d_in[0];
    const float* inputs  = (const float*)d_in[1];
    const float* enc1    = (const float*)d_in[2];
    const float* dec1    = (const float*)d_in[3];
    const float* masks   = (const float*)d_in[4];
    const int*   segs    = (const int*)d_in[5];
    float* ws  = (float*)d_ws;
    float* out = (float*)d_out;

    // atomic bins must be zeroed every call (harness poisons ws once, never re-zeros)
    hipMemsetAsync(ws, 0, WS_ZERO_FLOATS * sizeof(float), stream);

    confloss_main_kernel<<<NBLK, 256, 0, stream>>>(
        outputs, inputs, enc1, dec1, masks, segs, ws);
    confloss_finalize_kernel<<<1, 512, 0, stream>>>(ws, out);
}